// Round 2
// baseline (92.560 us; speedup 1.0000x reference)
//
#include <hip/hip_runtime.h>

// Block-factorized depthwise 7x7 conv, per-(n,c,8x8-block) filters.
// feat: [N=2, C=128, H=256, W=256] f32 (NCHW)
// filters_lr: [N, C*49, 32, 32] f32 ; weight[n,hb,wb,c,t] = filt[n, c*49+t, hb, wb]
// out[n,c,h,w] = sum_t feat[n,c,h+dh-3,w+dw-3] * weight[n,h/8,w/8,c,t], t=dh*7+dw
//
// Block = 256 threads = 2 block-rows (16 output rows x 256 cols).
// Thread = 4 rows x 4 cols. Wave covers 4 rows x 256 cols (row uniform per wave).
// LDS: input rows at float-idx 4 (16B) so staging writes and window reads are
// aligned ds_*_b128, conflict-free. Weights transposed [hbi][t][wb] so reads
// are lane-consecutive b32 (2-way broadcast = free), held in rolling regs.

#define LDW   264         // floats per LDS row: [0]unused [1..3]pad [4..259]data [260..262]pad [263]slack
#define NROWS 22          // 16 output rows + 6 halo

__global__ __launch_bounds__(256, 4)
void block_fac_kernel(const float* __restrict__ feat,
                      const float* __restrict__ filt,
                      float* __restrict__ out) {
    __shared__ float s_in[NROWS * LDW];   // 23232 B
    __shared__ float s_w[2 * 49 * 32];    // 12544 B   total 35776 B -> 4 blocks/CU

    const int bid = blockIdx.x;           // n*128*16 + c*16 + hb2
    const int hb2 = bid & 15;             // pair of 8-row blocks
    const int c   = (bid >> 4) & 127;
    const int n   = bid >> 11;
    const int tid = threadIdx.x;

    const int H0 = hb2 * 16;              // first output row
    const int h0 = H0 - 3;                // first staged input row

    // ---- stage weights: s_w[(hbi*49 + t)*32 + wb] = filt[n, c*49+t, hb2*2+hbi, wb]
    {
        const float* wg = filt + (size_t)((n * 128 + c) * 49) * 1024 + (size_t)(hb2 * 2) * 32;
        for (int idx = tid; idx < 2 * 49 * 32; idx += 256) {
            int wb  = idx & 31;
            int u   = idx >> 5;           // 0..97
            int hbi = (u >= 49);
            int t   = u - 49 * hbi;
            s_w[idx] = wg[(size_t)t * 1024 + hbi * 32 + wb];
        }
    }

    // ---- zero the 3-col pads (idx 1..3 and 260..262)
    if (tid < NROWS * 6) {
        int r = tid / 6, j = tid - r * 6;
        int p = (j < 3) ? (1 + j) : (257 + j);
        s_in[r * LDW + p] = 0.f;
    }

    // ---- stage input rows h0 .. h0+21 (zero outside [0,256)); aligned b128 writes
    const float* fbase = feat + (size_t)(n * 128 + c) * (256 * 256);
    for (int idx = tid; idx < NROWS * 64; idx += 256) {
        int r  = idx >> 6;                // row (uniform per wave per iteration)
        int c4 = (idx & 63) << 2;         // col base
        int gr = h0 + r;
        float4 v = make_float4(0.f, 0.f, 0.f, 0.f);
        if (gr >= 0 && gr < 256) v = *(const float4*)(fbase + (size_t)gr * 256 + c4);
        *(float4*)(&s_in[r * LDW + 4 + c4]) = v;
    }
    __syncthreads();

    // ---- compute: thread -> rows H0+r0..+3, cols c0..c0+3
    const int lane = tid & 63;
    const int wave = tid >> 6;
    const int c0   = lane << 2;
    const int wb   = lane >> 1;
    const int r0   = wave << 2;           // 0,4,8,12
    const int hbi  = wave >> 1;           // weight block-row
    const float* wlds = s_w + hbi * 49 * 32 + wb;

    float acc[4][4] = {};
    float wr[4][7];                       // rolling tap-row weights, slot = dh & 3

    #pragma unroll
    for (int jj = 0; jj < 10; ++jj) {     // s_in row r0+jj ; out row a uses dh = jj-a
        if (jj <= 6) {                    // bring in tap-row jj
            const float* wp = wlds + jj * 7 * 32;
            #pragma unroll
            for (int dw = 0; dw < 7; ++dw) wr[jj & 3][dw] = wp[dw * 32];
        }
        const float* rp = &s_in[(r0 + jj) * LDW + c0];   // 16B aligned
        float4 a0 = *(const float4*)(rp);
        float4 a1 = *(const float4*)(rp + 4);
        float4 a2 = *(const float4*)(rp + 8);
        float win[12] = {a0.x, a0.y, a0.z, a0.w,
                         a1.x, a1.y, a1.z, a1.w,
                         a2.x, a2.y, a2.z, a2.w};
        #pragma unroll
        for (int a = 0; a < 4; ++a) {
            int dh = jj - a;
            if (dh >= 0 && dh <= 6) {
                #pragma unroll
                for (int dw = 0; dw < 7; ++dw) {
                    float wv = wr[dh & 3][dw];
                    #pragma unroll
                    for (int i = 0; i < 4; ++i)
                        acc[a][i] += win[i + dw + 1] * wv;   // col c0+i+dw-3
                }
            }
        }
    }

    float* obase = out + ((size_t)((n * 128 + c) * 256 + H0 + r0)) * 256 + c0;
    #pragma unroll
    for (int a = 0; a < 4; ++a)
        *(float4*)(obase + (size_t)(a * 256)) =
            make_float4(acc[a][0], acc[a][1], acc[a][2], acc[a][3]);
}

extern "C" void kernel_launch(void* const* d_in, const int* in_sizes, int n_in,
                              void* d_out, int out_size, void* d_ws, size_t ws_size,
                              hipStream_t stream) {
    const float* feat = (const float*)d_in[0];
    const float* filt = (const float*)d_in[1];
    float* out = (float*)d_out;
    dim3 grid(2 * 128 * 16);
    dim3 block(256);
    hipLaunchKernelGGL(block_fac_kernel, grid, block, 0, stream, feat, filt, out);
}

// Round 3
// 57.033 us; speedup vs baseline: 1.6229x; 1.6229x over previous
//
#include <hip/hip_runtime.h>

// Block-factorized depthwise 7x7 conv, per-(n,c,8x8-block) filters.
// feat: [N=2, C=128, H=256, W=256] f32 (NCHW)
// filters_lr: [N, C*49, 32, 32] f32 ; weight[n,hb,wb,c,t] = filt[n, c*49+t, hb, wb]
// out[n,c,h,w] = sum_t feat[n,c,h+dh-3,w+dw-3] * weight[n,h/8,w/8,c,t], t=dh*7+dw
//
// Block = 256 threads = 16 output rows x 256 cols (2 vertical 8-blocks).
// Thread = 4 rows x 4 cols. Weights are NOT staged in LDS: each thread
// prefetches its wb-column's 49 taps straight into VGPRs (lane pairs share an
// address -> one coalesced 128B line per tap per wave; each filt element is
// read by exactly one wave pair in the whole grid).
// LDS holds only the 22x256 input tile, written/read as aligned b128
// (conflict-free). __launch_bounds__(256,2): empirically the VGPR cap is
// 256/min_waves, so 2 -> 128 VGPRs (round 2's (256,4) capped at 64 -> spills).

#define LDW   264   // floats/LDS row: [0] slack, [1..3] zero pad, [4..259] data, [260..262] pad, [263] slack
#define NROWS 22    // 16 output rows + 6 halo

__global__ __launch_bounds__(256, 2)
void block_fac_kernel(const float* __restrict__ feat,
                      const float* __restrict__ filt,
                      float* __restrict__ out) {
    __shared__ float s_in[NROWS * LDW];   // 23232 B

    const int bid = blockIdx.x;           // n*128*16 + c*16 + hb2
    const int hb2 = bid & 15;
    const int c   = (bid >> 4) & 127;
    const int n   = bid >> 11;
    const int tid = threadIdx.x;

    const int lane = tid & 63;
    const int wave = tid >> 6;
    const int c0   = lane << 2;           // output col base (0..252)
    const int wb   = lane >> 1;           // weight block col (0..31)
    const int r0   = wave << 2;           // output row base in tile (0,4,8,12)
    const int hb   = hb2 * 2 + (wave >> 1);  // weight block row

    // ---- prefetch this thread's 49 weights global -> VGPR (coalesced 128B/instr)
    const float* wgbase = filt + (size_t)((n * 128 + c) * 49) * 1024 + hb * 32 + wb;
    float wt[49];
    #pragma unroll
    for (int t = 0; t < 49; ++t) wt[t] = wgbase[(size_t)t * 1024];

    // ---- zero the 3-col pads (float idx 1..3 and 260..262)
    const int H0 = hb2 * 16;              // first output row
    const int h0 = H0 - 3;                // first staged input row
    if (tid < NROWS * 6) {
        int r = tid / 6, j = tid - r * 6;
        int p = (j < 3) ? (1 + j) : (257 + j);
        s_in[r * LDW + p] = 0.f;
    }

    // ---- stage input rows h0..h0+21 (zero outside [0,256)); aligned b128
    const float* fbase = feat + (size_t)(n * 128 + c) * (256 * 256);
    for (int idx = tid; idx < NROWS * 64; idx += 256) {
        int r  = idx >> 6;                // row (wave-uniform per iteration)
        int c4 = (idx & 63) << 2;
        int gr = h0 + r;
        float4 v = make_float4(0.f, 0.f, 0.f, 0.f);
        if (gr >= 0 && gr < 256) v = *(const float4*)(fbase + (size_t)gr * 256 + c4);
        *(float4*)(&s_in[r * LDW + 4 + c4]) = v;
    }
    __syncthreads();

    // ---- compute: thread -> rows H0+r0..+3, cols c0..c0+3
    float acc[4][4] = {};

    #pragma unroll
    for (int jj = 0; jj < 10; ++jj) {     // staged row r0+jj; out row a uses dh=jj-a
        const float* rp = &s_in[(r0 + jj) * LDW + c0];   // 16B aligned
        float4 a0 = *(const float4*)(rp);
        float4 a1 = *(const float4*)(rp + 4);
        float4 a2 = *(const float4*)(rp + 8);
        float win[12] = {a0.x, a0.y, a0.z, a0.w,
                         a1.x, a1.y, a1.z, a1.w,
                         a2.x, a2.y, a2.z, a2.w};
        #pragma unroll
        for (int a = 0; a < 4; ++a) {
            int dh = jj - a;
            if (dh >= 0 && dh <= 6) {
                #pragma unroll
                for (int dw = 0; dw < 7; ++dw) {
                    float wv = wt[dh * 7 + dw];
                    #pragma unroll
                    for (int i = 0; i < 4; ++i)
                        acc[a][i] += win[i + dw + 1] * wv;   // col c0+i+dw-3
                }
            }
        }
    }

    float* obase = out + (size_t)((n * 128 + c) * 256 + H0 + r0) * 256 + c0;
    #pragma unroll
    for (int a = 0; a < 4; ++a)
        *(float4*)(obase + (size_t)(a * 256)) =
            make_float4(acc[a][0], acc[a][1], acc[a][2], acc[a][3]);
}

extern "C" void kernel_launch(void* const* d_in, const int* in_sizes, int n_in,
                              void* d_out, int out_size, void* d_ws, size_t ws_size,
                              hipStream_t stream) {
    const float* feat = (const float*)d_in[0];
    const float* filt = (const float*)d_in[1];
    float* out = (float*)d_out;
    dim3 grid(2 * 128 * 16);
    dim3 block(256);
    hipLaunchKernelGGL(block_fac_kernel, grid, block, 0, stream, feat, filt, out);
}

// Round 4
// 47.604 us; speedup vs baseline: 1.9444x; 1.1981x over previous
//
#include <hip/hip_runtime.h>
#include <stdint.h>

// Block-factorized depthwise 7x7 conv, per-(n,c,8x8-block) filters.
// feat: [N=2, C=128, H=256, W=256] f32 (NCHW)
// filters_lr: [N, C*49, 32, 32] f32 ; weight[n,hb,wb,c,t] = filt[n, c*49+t, hb, wb]
// out[n,c,h,w] = sum_t feat[n,c,h+dh-3,w+dw-3] * weight[n,h/8,w/8,c,t], t=dh*7+dw
//
// Block = 256 threads = 16 output rows x 256 cols. Thread = 4 rows x 4 cols.
// Weights: 49 coalesced global->VGPR loads per thread (each filt element read
// exactly once grid-wide). Input tile: global_load_lds (wave-uniform LDS base
// + lane*16B, row uniform per wave-iteration) -> no VGPR round-trip and no
// ds_write/vmcnt interlock with the weight-load queue; one vmcnt(0) at the
// barrier drains both streams CONCURRENTLY (round 3 serialized them).

#define LDW   264   // floats/LDS row: [0] slack, [1..3] zero pad, [4..259] data, [260..262] pad, [263] slack
#define NROWS 22    // 16 output rows + 6 halo

typedef const uint32_t __attribute__((address_space(1))) guint;
typedef uint32_t __attribute__((address_space(3))) luint;

__global__ __launch_bounds__(256, 2)
void block_fac_kernel(const float* __restrict__ feat,
                      const float* __restrict__ filt,
                      float* __restrict__ out) {
    __shared__ float s_in[NROWS * LDW];   // 23232 B

    const int bid = blockIdx.x;           // n*128*16 + c*16 + hb2
    const int hb2 = bid & 15;
    const int c   = (bid >> 4) & 127;
    const int n   = bid >> 11;
    const int tid = threadIdx.x;

    const int lane = tid & 63;
    const int wave = tid >> 6;
    const int c0   = lane << 2;           // output col base (0..252)
    const int wb   = lane >> 1;           // weight block col (0..31)
    const int r0   = wave << 2;           // output row base in tile (0,4,8,12)
    const int hb   = hb2 * 2 + (wave >> 1);  // weight block row

    // ---- weight prefetch: issued first, drains concurrently with staging.
    // Lane pairs share an address -> one coalesced 128B line per tap per wave.
    const float* wgbase = filt + (size_t)((n * 128 + c) * 49) * 1024 + hb * 32 + wb;
    float wt[49];
    #pragma unroll
    for (int t = 0; t < 49; ++t) wt[t] = wgbase[(size_t)t * 1024];

    const int H0 = hb2 * 16;              // first output row
    const int h0 = H0 - 3;                // first staged input row

    // ---- zero the 3-col pads (float idx 1..3 and 260..262)
    if (tid < NROWS * 6) {
        int r = tid / 6, j = tid - r * 6;
        int p = (j < 3) ? (1 + j) : (257 + j);
        s_in[r * LDW + p] = 0.f;
    }

    // ---- stage input rows h0..h0+21 via global_load_lds (16B/lane, linear dest)
    const float* fbase = feat + (size_t)(n * 128 + c) * (256 * 256);
    for (int idx = tid; idx < NROWS * 64; idx += 256) {
        int r  = idx >> 6;                // wave-uniform per iteration
        int gr = h0 + r;
        float* lp = &s_in[r * LDW + 4];   // wave-uniform LDS base; HW adds lane*16
        if (gr >= 0 && gr < 256) {        // uniform branch
            const float* gp = fbase + (size_t)gr * 256 + ((idx & 63) << 2);
            __builtin_amdgcn_global_load_lds((guint*)gp, (luint*)lp, 16, 0, 0);
        } else {
            *(float4*)(&s_in[r * LDW + 4 + ((idx & 63) << 2)]) =
                make_float4(0.f, 0.f, 0.f, 0.f);
        }
    }
    __syncthreads();                      // one vmcnt(0): weights + tile drain together

    // ---- compute: thread -> rows H0+r0..+3, cols c0..c0+3
    float acc[4][4] = {};

    #pragma unroll
    for (int jj = 0; jj < 10; ++jj) {     // staged row r0+jj; out row a uses dh=jj-a
        const float* rp = &s_in[(r0 + jj) * LDW + c0];   // 16B aligned
        float4 a0 = *(const float4*)(rp);
        float4 a1 = *(const float4*)(rp + 4);
        float4 a2 = *(const float4*)(rp + 8);
        float win[12] = {a0.x, a0.y, a0.z, a0.w,
                         a1.x, a1.y, a1.z, a1.w,
                         a2.x, a2.y, a2.z, a2.w};
        #pragma unroll
        for (int a = 0; a < 4; ++a) {
            int dh = jj - a;
            if (dh >= 0 && dh <= 6) {
                #pragma unroll
                for (int dw = 0; dw < 7; ++dw) {
                    float wv = wt[dh * 7 + dw];
                    #pragma unroll
                    for (int i = 0; i < 4; ++i)
                        acc[a][i] += win[i + dw + 1] * wv;   // col c0+i+dw-3
                }
            }
        }
    }

    float* obase = out + (size_t)((n * 128 + c) * 256 + H0 + r0) * 256 + c0;
    #pragma unroll
    for (int a = 0; a < 4; ++a)
        *(float4*)(obase + (size_t)(a * 256)) =
            make_float4(acc[a][0], acc[a][1], acc[a][2], acc[a][3]);
}

extern "C" void kernel_launch(void* const* d_in, const int* in_sizes, int n_in,
                              void* d_out, int out_size, void* d_ws, size_t ws_size,
                              hipStream_t stream) {
    const float* feat = (const float*)d_in[0];
    const float* filt = (const float*)d_in[1];
    float* out = (float*)d_out;
    dim3 grid(2 * 128 * 16);
    dim3 block(256);
    hipLaunchKernelGGL(block_fac_kernel, grid, block, 0, stream, feat, filt, out);
}